// Round 10
// baseline (314.142 us; speedup 1.0000x reference)
//
#include <hip/hip_runtime.h>

// ---------------------------------------------------------------------------
// GCN: x1 = relu(Ahat @ (fts@W1) + b1); x2 = relu(Ahat @ (x1@W2) + b2);
//      out = x2@Wc + bc.  Ahat = D^-1/2 (A + I) D^-1/2.
// d_out = [out (N*16) | x2 (N*128)] fp32.
// R4: MFMA fp16 GEMMs. R5-R7: slot-capture CSR, 8-replica counters.
// R9: barrier-free wide-gather agg (16 lanes/row dwordx4, 16 rows in flight).
// R10: (1) k_out fused into agg2 epilogue (wave already holds full x2 row
//      post-butterfly; Wc transposed in LDS, conflict-free); (2) scan1+scan3
//      fused via device-scope publish/spin (196 blocks, all co-resident);
//      (3) x2 mid-tier gather unroll. 10 -> 8 launches.
// ---------------------------------------------------------------------------

#define IN_DIM 256
#define HID 128
#define OUT_DIM 16
#define SCAN_B 256
#define NREP 8

typedef _Float16 half8  __attribute__((ext_vector_type(8)));
typedef float    floatx4 __attribute__((ext_vector_type(4)));

__device__ __forceinline__ void wswz_one(const float* W, _Float16* Bsw, int o, int permK) {
    int j    = o & 7;
    int lane = (o >> 3) & 63;
    int t    = (o >> 9) & 7;
    int c    = o >> 12;
    int k = c * 32 + ((lane >> 4) << 3) + j;
    if (permK) k = ((k & 7) << 4) + (k >> 3);
    int ncol = t * 16 + (lane & 15);
    Bsw[o] = (_Float16)W[k * 128 + ncol];
}

// Fused prep: zero rep planes + scan state; swizzle W1,W2; permute biases.
__global__ void k_prep(int* __restrict__ rep, int nrepN, int* __restrict__ stateI,
                       const float* __restrict__ W1, _Float16* __restrict__ Bsw1,
                       const float* __restrict__ W2, _Float16* __restrict__ Bsw2,
                       const float* __restrict__ b1, float* __restrict__ bp1,
                       const float* __restrict__ b2, float* __restrict__ bp2) {
    int t = blockIdx.x * blockDim.x + threadIdx.x;
    int z4 = nrepN >> 2;
    if (t < z4) { ((int4*)rep)[t] = make_int4(0, 0, 0, 0); return; }
    int o = t - z4;
    int zr = nrepN & 3;
    if (o < zr) { rep[4 * z4 + o] = 0; return; }
    o -= zr;
    if (o < 2 * SCAN_B) { stateI[o] = 0; return; }   // 256 x u64 scan state
    o -= 2 * SCAN_B;
    if (o < IN_DIM * HID) { wswz_one(W1, Bsw1, o, 0); return; }
    o -= IN_DIM * HID;
    if (o < HID * HID) { wswz_one(W2, Bsw2, o, 1); return; }
    o -= HID * HID;
    if (o < HID) { bp1[o] = b1[((o & 7) << 4) + (o >> 3)]; return; }
    o -= HID;
    if (o < HID) { bp2[o] = b2[((o & 7) << 4) + (o >> 3)]; return; }
}

// Thread i owns edges 8i..8i+7; edge 8i+k bumps replica plane k.
__global__ void k_count(const int* __restrict__ dst, int* __restrict__ rep,
                        int* __restrict__ slot, int nN, int e8, int e) {
    int i = blockIdx.x * blockDim.x + threadIdx.x;
    if (i < e8) {
        int4 d0 = ((const int4*)dst)[2 * i];
        int4 d1 = ((const int4*)dst)[2 * i + 1];
        int4 s0, s1;
        s0.x = atomicAdd(&rep[0 * nN + d0.x], 1);
        s0.y = atomicAdd(&rep[1 * nN + d0.y], 1);
        s0.z = atomicAdd(&rep[2 * nN + d0.z], 1);
        s0.w = atomicAdd(&rep[3 * nN + d0.w], 1);
        s1.x = atomicAdd(&rep[4 * nN + d1.x], 1);
        s1.y = atomicAdd(&rep[5 * nN + d1.y], 1);
        s1.z = atomicAdd(&rep[6 * nN + d1.z], 1);
        s1.w = atomicAdd(&rep[7 * nN + d1.w], 1);
        ((int4*)slot)[2 * i]     = s0;
        ((int4*)slot)[2 * i + 1] = s1;
    }
    int base = e8 * 8;
    int t = blockIdx.x * blockDim.x + threadIdx.x;
    if (t < e - base) {
        int j = base + t;
        slot[j] = atomicAdd(&rep[(j & 7) * nN + dst[j]], 1);
    }
}

// Fused scan: plane-fold (regs) + block scan + device-scope publish/spin
// + absolute bases baked into planes + dinv. Replaces scan1+scan3.
// Safe: 196 blocks << residency capacity; publish happens before any spin.
__global__ __launch_bounds__(SCAN_B) void k_scan(int* __restrict__ rep,
                                                 int* __restrict__ row_ptr,
                                                 float* __restrict__ dinv,
                                                 unsigned long long* __restrict__ state,
                                                 int nN, int n, int e) {
    __shared__ int tmp[SCAN_B];
    int tid = threadIdx.x;
    int b = blockIdx.x;
    int i = b * SCAN_B + tid;
    int tr[NREP];
    int c = 0;
    if (i < n) {
        #pragma unroll
        for (int r = 0; r < NREP; ++r) {
            int t = rep[r * nN + i];
            tr[r] = c;
            c += t;
        }
    }
    tmp[tid] = c;
    __syncthreads();
    #pragma unroll
    for (int off = 1; off < SCAN_B; off <<= 1) {
        int v = (tid >= off) ? tmp[tid - off] : 0;
        __syncthreads();
        tmp[tid] += v;
        __syncthreads();
    }
    int lex = tmp[tid] - c;
    if (tid == SCAN_B - 1) {
        unsigned long long pv = (1ull << 63) | (unsigned long long)(unsigned int)tmp[SCAN_B - 1];
        __hip_atomic_store(&state[b], pv, __ATOMIC_RELEASE, __HIP_MEMORY_SCOPE_AGENT);
    }
    __syncthreads();
    int part = 0;
    if (tid < b) {
        unsigned long long v;
        do {
            v = __hip_atomic_load(&state[tid], __ATOMIC_ACQUIRE, __HIP_MEMORY_SCOPE_AGENT);
        } while (!(v >> 63));
        part = (int)(unsigned int)v;
    }
    tmp[tid] = part;
    __syncthreads();
    #pragma unroll
    for (int off = SCAN_B / 2; off >= 1; off >>= 1) {
        if (tid < off) tmp[tid] += tmp[tid + off];
        __syncthreads();
    }
    int base = tmp[0];
    if (i < n) {
        int rp = base + lex;
        row_ptr[i] = rp;
        dinv[i] = rsqrtf((float)(c + 1));   // +1 self-loop
        #pragma unroll
        for (int r = 0; r < NREP; ++r) rep[r * nN + i] = tr[r] + rp;
    }
    if (b == 0 && tid == 0) row_ptr[n] = e;
}

// Atomic-free scatter: col[rep[k][dst] + slot] = src.
__global__ void k_fill(const int* __restrict__ src, const int* __restrict__ dst,
                       const int* __restrict__ slot, const int* __restrict__ rep,
                       int* __restrict__ col, int nN, int e8, int e) {
    int i = blockIdx.x * blockDim.x + threadIdx.x;
    if (i < e8) {
        int4 v0 = ((const int4*)src)[2 * i];
        int4 v1 = ((const int4*)src)[2 * i + 1];
        int4 d0 = ((const int4*)dst)[2 * i];
        int4 d1 = ((const int4*)dst)[2 * i + 1];
        int4 s0 = ((const int4*)slot)[2 * i];
        int4 s1 = ((const int4*)slot)[2 * i + 1];
        col[rep[0 * nN + d0.x] + s0.x] = v0.x;
        col[rep[1 * nN + d0.y] + s0.y] = v0.y;
        col[rep[2 * nN + d0.z] + s0.z] = v0.z;
        col[rep[3 * nN + d0.w] + s0.w] = v0.w;
        col[rep[4 * nN + d1.x] + s1.x] = v1.x;
        col[rep[5 * nN + d1.y] + s1.y] = v1.y;
        col[rep[6 * nN + d1.z] + s1.z] = v1.z;
        col[rep[7 * nN + d1.w] + s1.w] = v1.w;
    }
    int base = e8 * 8;
    int t = blockIdx.x * blockDim.x + threadIdx.x;
    if (t < e - base) {
        int j = base + t;
        col[rep[(j & 7) * nN + dst[j]] + slot[j]] = src[j];
    }
}

// Cb[n,128](fp16, pi-permuted cols) = dinv[row] * (A[n,K] @ W[K,128]).
template<bool A32>
__global__ __launch_bounds__(256) void k_gemm_mfma(const void* __restrict__ Av,
                                                   const _Float16* __restrict__ Bsw,
                                                   _Float16* __restrict__ Cb,
                                                   const float* __restrict__ dinv,
                                                   int n, int K) {
    int tid   = threadIdx.x;
    int w     = tid >> 6;
    int ln    = tid & 63;
    int lane16 = ln & 15;
    int quad  = ln >> 4;
    int mrow  = blockIdx.x * 64 + w * 16 + lane16;
    int mload = mrow < n ? mrow : n - 1;
    int nchunk = K >> 5;

    floatx4 acc[8];
    #pragma unroll
    for (int t = 0; t < 8; ++t) acc[t] = (floatx4){0.f, 0.f, 0.f, 0.f};

    for (int c = 0; c < nchunk; ++c) {
        half8 a;
        if constexpr (A32) {
            const float* ap = (const float*)Av + (size_t)mload * K + c * 32 + quad * 8;
            float4 v0 = *(const float4*)ap;
            float4 v1 = *(const float4*)(ap + 4);
            a[0] = (_Float16)v0.x; a[1] = (_Float16)v0.y;
            a[2] = (_Float16)v0.z; a[3] = (_Float16)v0.w;
            a[4] = (_Float16)v1.x; a[5] = (_Float16)v1.y;
            a[6] = (_Float16)v1.z; a[7] = (_Float16)v1.w;
        } else {
            const _Float16* ap = (const _Float16*)Av + (size_t)mload * K + c * 32 + quad * 8;
            a = *(const half8*)ap;
        }
        const _Float16* bp = Bsw + ((size_t)(c * 8) * 64 + ln) * 8;
        #pragma unroll
        for (int t = 0; t < 8; ++t) {
            half8 b = *(const half8*)(bp + (size_t)t * 512);
            acc[t] = __builtin_amdgcn_mfma_f32_16x16x32_f16(a, b, acc[t], 0, 0, 0);
        }
    }

    int rbase = blockIdx.x * 64 + w * 16 + quad * 4;
    #pragma unroll
    for (int r = 0; r < 4; ++r) {
        int R = rbase + r;
        if (R < n) {
            float d = dinv[R];
            half8 o;
            #pragma unroll
            for (int t = 0; t < 8; ++t) o[t] = (_Float16)(acc[t][r] * d);
            *(half8*)(Cb + (size_t)R * 128 + lane16 * 8) = o;
        }
    }
}

// Shared gather body: one wave per node, 16 lanes/row, up to 16 rows in flight.
__device__ __forceinline__ void agg_body(const _Float16* __restrict__ xb,
                                         const int* __restrict__ col,
                                         int e0, int e1, int grp, float acc[8]) {
    int e = e0 + grp;
    for (; e + 12 < e1; e += 16) {
        int s0 = col[e], s1 = col[e + 4], s2 = col[e + 8], s3 = col[e + 12];
        half8 u0 = *(const half8*)(xb + (size_t)s0 * 128);
        half8 u1 = *(const half8*)(xb + (size_t)s1 * 128);
        half8 u2 = *(const half8*)(xb + (size_t)s2 * 128);
        half8 u3 = *(const half8*)(xb + (size_t)s3 * 128);
        #pragma unroll
        for (int j = 0; j < 8; ++j)
            acc[j] += (float)u0[j] + (float)u1[j] + (float)u2[j] + (float)u3[j];
    }
    for (; e + 4 < e1; e += 8) {
        int s0 = col[e], s1 = col[e + 4];
        half8 u0 = *(const half8*)(xb + (size_t)s0 * 128);
        half8 u1 = *(const half8*)(xb + (size_t)s1 * 128);
        #pragma unroll
        for (int j = 0; j < 8; ++j) acc[j] += (float)u0[j] + (float)u1[j];
    }
    for (; e < e1; e += 4) {
        int s = col[e];
        half8 u = *(const half8*)(xb + (size_t)s * 128);
        #pragma unroll
        for (int j = 0; j < 8; ++j) acc[j] += (float)u[j];
    }
}

// Layer-1 agg: writes h1 fp16 (permuted cols).
__global__ __launch_bounds__(256) void k_agg1(const _Float16* __restrict__ xwb,
                                              const float* __restrict__ dinv,
                                              const int* __restrict__ row_ptr,
                                              const int* __restrict__ col,
                                              const float* __restrict__ bp,
                                              _Float16* __restrict__ hout, int n) {
    int wave = threadIdx.x >> 6;
    int ln   = threadIdx.x & 63;
    int grp  = ln >> 4;
    int pos  = ln & 15;
    int i = blockIdx.x * 4 + wave;
    if (i >= n) return;
    int e0 = row_ptr[i], e1 = row_ptr[i + 1];
    const _Float16* xb = xwb + pos * 8;
    float acc[8];
    #pragma unroll
    for (int j = 0; j < 8; ++j) acc[j] = 0.f;
    agg_body(xb, col, e0, e1, grp, acc);
    #pragma unroll
    for (int j = 0; j < 8; ++j) {
        acc[j] += __shfl_xor(acc[j], 16, 64);
        acc[j] += __shfl_xor(acc[j], 32, 64);
    }
    half8 us = *(const half8*)(xb + (size_t)i * 128);
    float di = dinv[i];
    float4 bq0 = *(const float4*)(bp + pos * 8);
    float4 bq1 = *(const float4*)(bp + pos * 8 + 4);
    float bb[8] = {bq0.x, bq0.y, bq0.z, bq0.w, bq1.x, bq1.y, bq1.z, bq1.w};
    if (grp == 0) {
        half8 o;
        #pragma unroll
        for (int j = 0; j < 8; ++j)
            o[j] = (_Float16)fmaxf(fmaf(di, acc[j] + (float)us[j], bb[j]), 0.f);
        *(half8*)(hout + (size_t)i * 128 + pos * 8) = o;
    }
}

// Layer-2 agg + fused classifier: writes h2 fp32 (un-permuted) AND out[n,16].
__global__ __launch_bounds__(256) void k_agg_out(const _Float16* __restrict__ xwb,
                                                 const float* __restrict__ dinv,
                                                 const int* __restrict__ row_ptr,
                                                 const int* __restrict__ col,
                                                 const float* __restrict__ bp,
                                                 const float* __restrict__ Wc,
                                                 const float* __restrict__ bc,
                                                 float* __restrict__ h2,
                                                 float* __restrict__ out, int n) {
    __shared__ float WcT[16][128];   // WcT[o][c] = Wc[c][o]; conflict-free reads
    __shared__ float bcs[16];
    int tid = threadIdx.x;
    for (int t = tid; t < 2048; t += 256) {
        int o = t >> 7, c = t & 127;
        WcT[o][c] = Wc[c * 16 + o];
    }
    if (tid < 16) bcs[tid] = bc[tid];
    __syncthreads();   // one-time staging barrier; waves independent after

    int wave = tid >> 6;
    int ln   = tid & 63;
    int grp  = ln >> 4;
    int pos  = ln & 15;
    int i = blockIdx.x * 4 + wave;
    if (i >= n) return;
    int e0 = row_ptr[i], e1 = row_ptr[i + 1];
    const _Float16* xb = xwb + pos * 8;
    float acc[8];
    #pragma unroll
    for (int j = 0; j < 8; ++j) acc[j] = 0.f;
    agg_body(xb, col, e0, e1, grp, acc);
    #pragma unroll
    for (int j = 0; j < 8; ++j) {
        acc[j] += __shfl_xor(acc[j], 16, 64);
        acc[j] += __shfl_xor(acc[j], 32, 64);
    }
    half8 us = *(const half8*)(xb + (size_t)i * 128);
    float di = dinv[i];
    float4 bq0 = *(const float4*)(bp + pos * 8);
    float4 bq1 = *(const float4*)(bp + pos * 8 + 4);
    float bb[8] = {bq0.x, bq0.y, bq0.z, bq0.w, bq1.x, bq1.y, bq1.z, bq1.w};
    float ov[8];
    #pragma unroll
    for (int j = 0; j < 8; ++j)
        ov[j] = fmaxf(fmaf(di, acc[j] + (float)us[j], bb[j]), 0.f);

    // h2 write: position p = pos*8+j -> column j*16+pos (64B coalesced per j)
    if (grp == 0) {
        float* hf = h2 + (size_t)i * 128;
        #pragma unroll
        for (int j = 0; j < 8; ++j) hf[j * 16 + pos] = ov[j];
    }

    // Fused classifier: lane holds columns {j*16+pos}; partials over 16 outputs.
    float po[16];
    #pragma unroll
    for (int o = 0; o < 16; ++o) {
        float s = 0.f;
        #pragma unroll
        for (int j = 0; j < 8; ++j) s = fmaf(ov[j], WcT[o][j * 16 + pos], s);
        po[o] = s;
    }
    #pragma unroll
    for (int o = 0; o < 16; ++o) {
        po[o] += __shfl_xor(po[o], 1, 64);
        po[o] += __shfl_xor(po[o], 2, 64);
        po[o] += __shfl_xor(po[o], 4, 64);
        po[o] += __shfl_xor(po[o], 8, 64);
    }
    if (grp == 0) {
        float val = po[0];
        #pragma unroll
        for (int o = 1; o < 16; ++o) if (pos == o) val = po[o];
        out[(size_t)i * 16 + pos] = val + bcs[pos];
    }
}

static inline size_t align256(size_t x) { return (x + 255) & ~(size_t)255; }

extern "C" void kernel_launch(void* const* d_in, const int* in_sizes, int n_in,
                              void* d_out, int out_size, void* d_ws, size_t ws_size,
                              hipStream_t stream) {
    const float* fts = (const float*)d_in[0];
    const int*   ei  = (const int*)d_in[1];
    const float* W1  = (const float*)d_in[2];
    const float* b1  = (const float*)d_in[3];
    const float* W2  = (const float*)d_in[4];
    const float* b2  = (const float*)d_in[5];
    const float* Wc  = (const float*)d_in[6];
    const float* bc  = (const float*)d_in[7];

    const int N = in_sizes[0] / IN_DIM;     // 50000
    const int E = in_sizes[1] / 2;          // 800000
    const int* src = ei;
    const int* dst = ei + E;

    char* p = (char*)d_ws;
    int* rep      = (int*)p;               p += align256(sizeof(int) * NREP * N);
    int* row_ptr  = (int*)p;               p += align256(sizeof(int) * (N + 1));
    float* dinv   = (float*)p;             p += align256(sizeof(float) * N);
    int* slot     = (int*)p;               p += align256(sizeof(int) * E);
    int* col      = (int*)p;               p += align256(sizeof(int) * E);
    unsigned long long* state = (unsigned long long*)p; p += align256(sizeof(unsigned long long) * SCAN_B);
    _Float16* Bsw1 = (_Float16*)p;         p += align256(sizeof(_Float16) * IN_DIM * HID);
    _Float16* Bsw2 = (_Float16*)p;         p += align256(sizeof(_Float16) * HID * HID);
    float* bp1    = (float*)p;             p += align256(sizeof(float) * HID);
    float* bp2    = (float*)p;             p += align256(sizeof(float) * HID);
    _Float16* xwb = (_Float16*)p;          p += align256(sizeof(_Float16) * (size_t)N * HID);
    _Float16* h1  = (_Float16*)p;          p += align256(sizeof(_Float16) * (size_t)N * HID);

    float* out = (float*)d_out;                   // [N,16]
    float* h2  = (float*)d_out + (size_t)N * 16;  // [N,128]

    const int T = 256;
    const int E8 = E / 8;
    dim3 gE8((E8 + T - 1) / T);
    const int nScanB = (N + SCAN_B - 1) / SCAN_B;   // 196 <= SCAN_B

    // Fused prep (rep+state zero + W swizzles + bias perms)
    const int nrepN = NREP * N;
    const int prepTot = (nrepN >> 2) + (nrepN & 3) + 2 * SCAN_B
                      + IN_DIM * HID + HID * HID + 2 * HID;
    k_prep<<<(prepTot + T - 1) / T, T, 0, stream>>>(rep, nrepN, (int*)state,
                                                    W1, Bsw1, W2, Bsw2,
                                                    b1, bp1, b2, bp2);
    // Graph structure
    k_count<<<gE8, T, 0, stream>>>(dst, rep, slot, N, E8, E);
    k_scan<<<nScanB, SCAN_B, 0, stream>>>(rep, row_ptr, dinv, state, N, N, E);
    k_fill<<<gE8, T, 0, stream>>>(src, dst, slot, rep, col, N, E8, E);

    dim3 gGemm((N + 63) / 64);
    dim3 gAgg((N + 3) / 4);

    // Layer 1
    k_gemm_mfma<true><<<gGemm, T, 0, stream>>>(fts, Bsw1, xwb, dinv, N, IN_DIM);
    k_agg1<<<gAgg, T, 0, stream>>>(xwb, dinv, row_ptr, col, bp1, h1, N);
    // Layer 2
    k_gemm_mfma<false><<<gGemm, T, 0, stream>>>(h1, Bsw2, xwb, dinv, N, HID);
    // Layer-2 agg + fused classifier
    k_agg_out<<<gAgg, T, 0, stream>>>(xwb, dinv, row_ptr, col, bp2, Wc, bc, h2, out, N);
}